// Round 6
// baseline (905.410 us; speedup 1.0000x reference)
//
#include <hip/hip_runtime.h>
#include <stdint.h>

// CGIterator on MI355X (gfx950) — block-fused v4: round-5 skeleton +
// (1) mixed1 staged directly to Bs (kills VGPR spills), (2) As XOR-swizzle
// (kills 16-way bank conflicts), (3) W-frag hoisting per l-group.
// Stream storage: offset = l*l*NK + (n*(2l+1)+loc)*128 + k, NK = N*K.

#define NK (16384 * 128)

typedef float f32x4 __attribute__((ext_vector_type(4)));
typedef short short8 __attribute__((ext_vector_type(8)));
typedef __bf16 bf16x8 __attribute__((ext_vector_type(8)));

typedef short8 short8a __attribute__((may_alias));
typedef f32x4 f32x4a __attribute__((may_alias));
typedef uint32_t u32a __attribute__((may_alias));
typedef uint16_t u16a __attribute__((may_alias));
typedef float floata __attribute__((may_alias));

__device__ __forceinline__ uint16_t f2b(float f) {   // f32 -> bf16 bits, RNE
  uint32_t u = __builtin_bit_cast(uint32_t, f);
  u += 0x7FFFu + ((u >> 16) & 1u);
  return (uint16_t)(u >> 16);
}
__device__ __forceinline__ float b2f(uint16_t h) {
  uint32_t u = ((uint32_t)h) << 16;
  return __builtin_bit_cast(float, u);
}
__device__ __forceinline__ f32x4 mfma_bf16(short8 a, short8 b, f32x4 c) {
  return __builtin_amdgcn_mfma_f32_16x16x32_bf16(
      __builtin_bit_cast(bf16x8, a), __builtin_bit_cast(bf16x8, b), c, 0, 0, 0);
}
__device__ __forceinline__ int l_of_m(int m) { return (m > 0) + (m > 3) + (m > 8); }
__device__ __forceinline__ int l_of_t(int t) { return (t >= 1) + (t >= 3) + (t >= 6); }

// Tile-row decode. 16-row tiles per l: t0:l0, t1-2:l1, t3-5:l2, t6-9:l3.
// Returns As row index n*16 + m_flat; pad slots clamp to row 0 (real=false).
__device__ __forceinline__ int trow(int t, int ridx, bool& real) {
  const int l = l_of_t(t);
  const int deg = 2 * l + 1;
  const int p0 = (t - (l * (l + 1)) / 2) * 16 + ridx;
  real = p0 < 8 * deg;
  const int p = real ? p0 : 0;
  const int n = p / deg;
  const int mloc = p - n * deg;
  return n * 16 + l * l + mloc;
}

// As byte address with XOR swizzle. row>>3 term matters: l0 rows are n*16,
// so (row&7) alone is constant-0 there.
__device__ __forceinline__ int aswz(int row, int kbyte) {
  return row * 256 + (kbyte ^ (((row ^ (row >> 3)) & 7) << 4));
}

// GEMM, accumulate: acc[t] += A(tile t) @ W_{l(t)}, output col qt*16+r.
__device__ __forceinline__ void gemm_app(const char* AsB, const uint16_t* Wb,
                                         int r, int g, int qt, f32x4* acc) {
#pragma unroll
  for (int lg = 0; lg < 4; ++lg) {
    const uint16_t* Wq = Wb + lg * 16384 + (qt * 16 + r) * 128 + g * 8;
    const short8 w0 = *(const short8a*)(Wq);
    const short8 w1 = *(const short8a*)(Wq + 32);
    const short8 w2 = *(const short8a*)(Wq + 64);
    const short8 w3 = *(const short8a*)(Wq + 96);
#pragma unroll
    for (int u = 0; u <= lg; ++u) {
      const int t = lg * (lg + 1) / 2 + u;
      bool dum;
      const int arow = trow(t, r, dum);
      f32x4 c = acc[t];
      c = mfma_bf16(*(const short8a*)(AsB + aswz(arow, g * 16)), w0, c);
      c = mfma_bf16(*(const short8a*)(AsB + aswz(arow, 64 + g * 16)), w1, c);
      c = mfma_bf16(*(const short8a*)(AsB + aswz(arow, 128 + g * 16)), w2, c);
      c = mfma_bf16(*(const short8a*)(AsB + aswz(arow, 192 + g * 16)), w3, c);
      acc[t] = c;
    }
  }
}

// GEMM, fresh accumulate, write C-frags (bf16) directly to Bs[n][k][m].
__device__ __forceinline__ void gemm_stage_bs(const char* AsB, const uint16_t* Wb,
                                              int r, int g, int qt,
                                              uint16_t* Bs) {
#pragma unroll
  for (int lg = 0; lg < 4; ++lg) {
    const uint16_t* Wq = Wb + lg * 16384 + (qt * 16 + r) * 128 + g * 8;
    const short8 w0 = *(const short8a*)(Wq);
    const short8 w1 = *(const short8a*)(Wq + 32);
    const short8 w2 = *(const short8a*)(Wq + 64);
    const short8 w3 = *(const short8a*)(Wq + 96);
#pragma unroll
    for (int u = 0; u <= lg; ++u) {
      const int t = lg * (lg + 1) / 2 + u;
      bool dum;
      const int arow = trow(t, r, dum);
      f32x4 c = {0.f, 0.f, 0.f, 0.f};
      c = mfma_bf16(*(const short8a*)(AsB + aswz(arow, g * 16)), w0, c);
      c = mfma_bf16(*(const short8a*)(AsB + aswz(arow, 64 + g * 16)), w1, c);
      c = mfma_bf16(*(const short8a*)(AsB + aswz(arow, 128 + g * 16)), w2, c);
      c = mfma_bf16(*(const short8a*)(AsB + aswz(arow, 192 + g * 16)), w3, c);
#pragma unroll
      for (int j = 0; j < 4; ++j) {
        bool cr;
        const int row = trow(t, g * 4 + j, cr);
        if (cr) {
          const int cn = row >> 4, cm = row & 15;
          Bs[cn * 2048 + (qt * 16 + r) * 16 + cm] = f2b(c[j]);
        }
      }
    }
  }
}

// GEMM, fresh accumulate, pack to bf16 pairs mp[t*2+{0,1}].
__device__ __forceinline__ void gemm_pack(const char* AsB, const uint16_t* Wb,
                                          int r, int g, int qt, uint32_t* mp) {
#pragma unroll
  for (int lg = 0; lg < 4; ++lg) {
    const uint16_t* Wq = Wb + lg * 16384 + (qt * 16 + r) * 128 + g * 8;
    const short8 w0 = *(const short8a*)(Wq);
    const short8 w1 = *(const short8a*)(Wq + 32);
    const short8 w2 = *(const short8a*)(Wq + 64);
    const short8 w3 = *(const short8a*)(Wq + 96);
#pragma unroll
    for (int u = 0; u <= lg; ++u) {
      const int t = lg * (lg + 1) / 2 + u;
      bool dum;
      const int arow = trow(t, r, dum);
      f32x4 c = {0.f, 0.f, 0.f, 0.f};
      c = mfma_bf16(*(const short8a*)(AsB + aswz(arow, g * 16)), w0, c);
      c = mfma_bf16(*(const short8a*)(AsB + aswz(arow, 64 + g * 16)), w1, c);
      c = mfma_bf16(*(const short8a*)(AsB + aswz(arow, 128 + g * 16)), w2, c);
      c = mfma_bf16(*(const short8a*)(AsB + aswz(arow, 192 + g * 16)), w3, c);
      mp[t * 2] = (uint32_t)f2b(c[0]) | ((uint32_t)f2b(c[1]) << 16);
      mp[t * 2 + 1] = (uint32_t)f2b(c[2]) | ((uint32_t)f2b(c[3]) << 16);
    }
  }
}

// ---------------------------------------------------------------------------
// K0: prep — bf16-transpose weights ([k][q] -> [q][k]) and build Ccat[16][256].
// ---------------------------------------------------------------------------
__global__ __launch_bounds__(256) void k0_prep(
    const float* __restrict__ mixw, const float* __restrict__ iterw,
    const float* __restrict__ cg,
    uint16_t* __restrict__ wtmix, uint16_t* __restrict__ wtiter,
    uint16_t* __restrict__ ccat) {
  int idx = blockIdx.x * 256 + threadIdx.x;
  const int NMIX = 3 * 4 * 16384, NITR = 2 * 4 * 16384;
  if (idx < NMIX) {
    int il = idx >> 14, rem = idx & 16383, q = rem >> 7, k = rem & 127;
    wtmix[idx] = f2b(mixw[il * 16384 + k * 128 + q]);
  } else if (idx < NMIX + NITR) {
    int o = idx - NMIX;
    int tl = o >> 14, rem = o & 16383, q = rem >> 7, k = rem & 127;
    wtiter[o] = f2b(iterw[tl * 16384 + k * 128 + q]);
  } else if (idx < NMIX + NITR + 4096) {
    int o = idx - NMIX - NITR;
    int mg = o >> 8, ij = o & 255, ig = ij >> 4, jg = ij & 15;
    int l = l_of_m(mg), m = mg - l * l;
    int l1 = l_of_m(ig), i = ig - l1 * l1;
    int l2 = l_of_m(jg), j = jg - l2 * l2;
    ccat[o] = f2b(cg[(l1 * 16 + l2 * 4 + l) * 343 + i * 49 + j * 7 + m]);
  }
}

// ---------------------------------------------------------------------------
// Fused block kernel: 512 threads = 8 waves; wave w owns channel tile qt=w
// for GEMMs and row n=w for the TP.
// LDS 64KB: As = [128 row][128 k] bf16 XOR-swizzled; Bs = [8 n][128 k][16 m]
// bf16 linear; final f32 [128][128] staging overlays both.
// ---------------------------------------------------------------------------
__global__ __launch_bounds__(512) void k_fused(
    const float* __restrict__ f0, const float* __restrict__ f1,
    const float* __restrict__ f2, const float* __restrict__ f3,
    const uint16_t* __restrict__ wtmix, const uint16_t* __restrict__ wtiter,
    const uint16_t* __restrict__ ccat, float* __restrict__ out) {
  __shared__ __align__(16) uint16_t smem[32768];   // 64KB
  char* const AsB = (char*)smem;        // swizzled [128 row][128 k] bf16
  uint16_t* const Bs = smem + 16384;    // Bs[n*2048 + k*16 + m]

  const int tid = threadIdx.x;
  const int lane = tid & 63, wid = tid >> 6;
  const int g = lane >> 4, r = lane & 15;
  const int qt = wid;
  const int nblk = blockIdx.x * 8;

  // zero all LDS (coverage insurance)
  {
    u32a* z = (u32a*)smem;
    for (int i = 0; i < 32; ++i) z[tid + i * 512] = 0;
  }
  __syncthreads();

  // ---- phase 0: stage feats (bf16) into As ----
  for (int i = 0; i < 32; ++i) {
    const int elem = tid + i * 512;
    const int row = elem >> 7, k = elem & 127;
    const int nn = row >> 4, mf = row & 15;
    const int l = l_of_m(mf), loc = mf - l * l;
    const float* F = (l == 0) ? f0 : (l == 1) ? f1 : (l == 2) ? f2 : f3;
    *(u16a*)(AsB + aswz(row, k * 2)) =
        f2b(F[((size_t)(nblk + nn) * (2 * l + 1) + loc) * 128 + k]);
  }
  __syncthreads();

  // ---- mixing: cur = feats@W0 (f32 regs), mixed1 -> Bs, mixed2 -> m2p regs --
  f32x4 cur[10];
#pragma unroll
  for (int t = 0; t < 10; ++t) cur[t] = f32x4{0.f, 0.f, 0.f, 0.f};
  uint32_t m2p[20];
  gemm_app(AsB, wtmix, r, g, qt, cur);
  gemm_stage_bs(AsB, wtmix + 4 * 16384, r, g, qt, Bs);
  gemm_pack(AsB, wtmix + 8 * 16384, r, g, qt, m2p);
  __syncthreads();   // feats reads done; As may be overwritten

  const int ih = g >> 1, jb = (g & 1) * 8;

  // ================= iteration 0 =================
  // stage cur -> As (bf16); Bs already holds mixed1
#pragma unroll
  for (int t = 0; t < 10; ++t)
#pragma unroll
    for (int j = 0; j < 4; ++j) {
      bool cr;
      const int row = trow(t, g * 4 + j, cr);
      if (cr) *(u16a*)(AsB + aswz(row, (qt * 16 + r) * 2)) = f2b(cur[t][j]);
    }
  __syncthreads();

  f32x4 tacc[8];
#pragma unroll
  for (int ki = 0; ki < 8; ++ki) tacc[ki] = f32x4{0.f, 0.f, 0.f, 0.f};
#pragma unroll
  for (int cc = 0; cc < 8; ++cc) {
    const short8 cfr = *(const short8a*)(ccat + r * 256 + cc * 32 + g * 8);
    const int arow = wid * 16 + cc * 2 + ih;
#pragma unroll
    for (int ki = 0; ki < 8; ++ki) {
      const int k = ki * 16 + r;
      const float av = b2f(*(const u16a*)(AsB + aswz(arow, k * 2)));
      const short8 bv = *(const short8a*)&Bs[wid * 2048 + k * 16 + jb];
      short8 pv;
#pragma unroll
      for (int e = 0; e < 8; ++e)
        pv[e] = (short)f2b(av * b2f((uint16_t)bv[e]));
      tacc[ki] = mfma_bf16(cfr, pv, tacc[ki]);
    }
  }
  __syncthreads();   // all As/Bs reads complete before overwrite

  // tp -> As rows of n = wid
#pragma unroll
  for (int ki = 0; ki < 8; ++ki)
#pragma unroll
    for (int j = 0; j < 4; ++j)
      *(u16a*)(AsB + aswz(wid * 16 + g * 4 + j, (ki * 16 + r) * 2)) =
          f2b(tacc[ki][j]);
  __syncthreads();

  // cur += tp @ iter_w[0]; also stage mixed2 -> Bs (TP done reading Bs)
  gemm_app(AsB, wtiter, r, g, qt, cur);
#pragma unroll
  for (int t = 0; t < 10; ++t)
#pragma unroll
    for (int j = 0; j < 4; ++j) {
      bool cr;
      const int row = trow(t, g * 4 + j, cr);
      if (cr) {
        const int cn = row >> 4, cm = row & 15;
        Bs[cn * 2048 + (qt * 16 + r) * 16 + cm] =
            (uint16_t)(m2p[t * 2 + (j >> 1)] >> ((j & 1) * 16));
      }
    }
  __syncthreads();

  // ================= iteration 1 =================
#pragma unroll
  for (int t = 0; t < 10; ++t)
#pragma unroll
    for (int j = 0; j < 4; ++j) {
      bool cr;
      const int row = trow(t, g * 4 + j, cr);
      if (cr) *(u16a*)(AsB + aswz(row, (qt * 16 + r) * 2)) = f2b(cur[t][j]);
    }
  __syncthreads();

#pragma unroll
  for (int ki = 0; ki < 8; ++ki) tacc[ki] = f32x4{0.f, 0.f, 0.f, 0.f};
#pragma unroll
  for (int cc = 0; cc < 8; ++cc) {
    const short8 cfr = *(const short8a*)(ccat + r * 256 + cc * 32 + g * 8);
    const int arow = wid * 16 + cc * 2 + ih;
#pragma unroll
    for (int ki = 0; ki < 8; ++ki) {
      const int k = ki * 16 + r;
      const float av = b2f(*(const u16a*)(AsB + aswz(arow, k * 2)));
      const short8 bv = *(const short8a*)&Bs[wid * 2048 + k * 16 + jb];
      short8 pv;
#pragma unroll
      for (int e = 0; e < 8; ++e)
        pv[e] = (short)f2b(av * b2f((uint16_t)bv[e]));
      tacc[ki] = mfma_bf16(cfr, pv, tacc[ki]);
    }
  }
  __syncthreads();

#pragma unroll
  for (int ki = 0; ki < 8; ++ki)
#pragma unroll
    for (int j = 0; j < 4; ++j)
      *(u16a*)(AsB + aswz(wid * 16 + g * 4 + j, (ki * 16 + r) * 2)) =
          f2b(tacc[ki][j]);
  __syncthreads();

  gemm_app(AsB, wtiter + 4 * 16384, r, g, qt, cur);
  __syncthreads();

  // ---- final: stage f32 in LDS (overlay), coalesced store ----
  floata* fs = (floata*)smem;   // [128 row][128 k] f32 = 64KB
#pragma unroll
  for (int t = 0; t < 10; ++t)
#pragma unroll
    for (int j = 0; j < 4; ++j) {
      bool cr;
      const int row = trow(t, g * 4 + j, cr);
      if (cr) fs[row * 128 + qt * 16 + r] = cur[t][j];
    }
  __syncthreads();
  {
    const int grp = tid >> 5, t32 = tid & 31;
    const int ns = grp >> 1, mh = (grp & 1) * 8;
    for (int m8 = 0; m8 < 8; ++m8) {
      const int m = mh + m8;
      const int l = l_of_m(m), loc = m - l * l;
      float* op = out + (size_t)l * l * NK +
                  ((size_t)(nblk + ns) * (2 * l + 1) + loc) * 128 + t32 * 4;
      *(f32x4a*)op = *(const f32x4a*)(fs + (ns * 16 + m) * 128 + t32 * 4);
    }
  }
}

// ---------------------------------------------------------------------------
extern "C" void kernel_launch(void* const* d_in, const int* in_sizes, int n_in,
                              void* d_out, int out_size, void* d_ws, size_t ws_size,
                              hipStream_t stream) {
  const float* f0    = (const float*)d_in[0];
  const float* f1    = (const float*)d_in[1];
  const float* f2    = (const float*)d_in[2];
  const float* f3    = (const float*)d_in[3];
  const float* mixw  = (const float*)d_in[4];
  const float* iterw = (const float*)d_in[5];
  const float* cg    = (const float*)d_in[6];
  float* out = (float*)d_out;

  // ws (uint16): wtmix 196608 | wtiter 131072 | ccat 4096
  uint16_t* wtmix  = (uint16_t*)d_ws;
  uint16_t* wtiter = wtmix + 196608;
  uint16_t* ccat   = wtiter + 131072;

  k0_prep<<<1296, 256, 0, stream>>>(mixw, iterw, cg, wtmix, wtiter, ccat);
  k_fused<<<2048, 512, 0, stream>>>(f0, f1, f2, f3, wtmix, wtiter, ccat, out);
}

// Round 7
// 903.432 us; speedup vs baseline: 1.0022x; 1.0022x over previous
//
#include <hip/hip_runtime.h>
#include <stdint.h>

// CGIterator on MI355X (gfx950) — block-fused v5: round-6 structure with
// __launch_bounds__(512, 2) -> 256-VGPR cap, eliminating structural spills
// (round-5/6 were capped at 128 VGPR -> ~1 GB/launch scratch traffic).
// Stream storage: offset = l*l*NK + (n*(2l+1)+loc)*128 + k, NK = N*K.

#define NK (16384 * 128)

typedef float f32x4 __attribute__((ext_vector_type(4)));
typedef short short8 __attribute__((ext_vector_type(8)));
typedef __bf16 bf16x8 __attribute__((ext_vector_type(8)));

typedef short8 short8a __attribute__((may_alias));
typedef f32x4 f32x4a __attribute__((may_alias));
typedef uint32_t u32a __attribute__((may_alias));
typedef uint16_t u16a __attribute__((may_alias));
typedef float floata __attribute__((may_alias));

__device__ __forceinline__ uint16_t f2b(float f) {   // f32 -> bf16 bits, RNE
  uint32_t u = __builtin_bit_cast(uint32_t, f);
  u += 0x7FFFu + ((u >> 16) & 1u);
  return (uint16_t)(u >> 16);
}
__device__ __forceinline__ float b2f(uint16_t h) {
  uint32_t u = ((uint32_t)h) << 16;
  return __builtin_bit_cast(float, u);
}
__device__ __forceinline__ f32x4 mfma_bf16(short8 a, short8 b, f32x4 c) {
  return __builtin_amdgcn_mfma_f32_16x16x32_bf16(
      __builtin_bit_cast(bf16x8, a), __builtin_bit_cast(bf16x8, b), c, 0, 0, 0);
}
__device__ __forceinline__ int l_of_m(int m) { return (m > 0) + (m > 3) + (m > 8); }
__device__ __forceinline__ int l_of_t(int t) { return (t >= 1) + (t >= 3) + (t >= 6); }

// Tile-row decode. 16-row tiles per l: t0:l0, t1-2:l1, t3-5:l2, t6-9:l3.
// Returns As row index n*16 + m_flat; pad slots clamp to row 0 (real=false).
__device__ __forceinline__ int trow(int t, int ridx, bool& real) {
  const int l = l_of_t(t);
  const int deg = 2 * l + 1;
  const int p0 = (t - (l * (l + 1)) / 2) * 16 + ridx;
  real = p0 < 8 * deg;
  const int p = real ? p0 : 0;
  const int n = p / deg;
  const int mloc = p - n * deg;
  return n * 16 + l * l + mloc;
}

// As byte address with XOR swizzle. row>>3 term matters: l0 rows are n*16,
// so (row&7) alone is constant-0 there.
__device__ __forceinline__ int aswz(int row, int kbyte) {
  return row * 256 + (kbyte ^ (((row ^ (row >> 3)) & 7) << 4));
}

// GEMM, accumulate: acc[t] += A(tile t) @ W_{l(t)}, output col qt*16+r.
__device__ __forceinline__ void gemm_app(const char* AsB, const uint16_t* Wb,
                                         int r, int g, int qt, f32x4* acc) {
#pragma unroll
  for (int lg = 0; lg < 4; ++lg) {
    const uint16_t* Wq = Wb + lg * 16384 + (qt * 16 + r) * 128 + g * 8;
    const short8 w0 = *(const short8a*)(Wq);
    const short8 w1 = *(const short8a*)(Wq + 32);
    const short8 w2 = *(const short8a*)(Wq + 64);
    const short8 w3 = *(const short8a*)(Wq + 96);
#pragma unroll
    for (int u = 0; u <= lg; ++u) {
      const int t = lg * (lg + 1) / 2 + u;
      bool dum;
      const int arow = trow(t, r, dum);
      f32x4 c = acc[t];
      c = mfma_bf16(*(const short8a*)(AsB + aswz(arow, g * 16)), w0, c);
      c = mfma_bf16(*(const short8a*)(AsB + aswz(arow, 64 + g * 16)), w1, c);
      c = mfma_bf16(*(const short8a*)(AsB + aswz(arow, 128 + g * 16)), w2, c);
      c = mfma_bf16(*(const short8a*)(AsB + aswz(arow, 192 + g * 16)), w3, c);
      acc[t] = c;
    }
  }
}

// GEMM, fresh accumulate, write C-frags (bf16) directly to Bs[n][k][m].
__device__ __forceinline__ void gemm_stage_bs(const char* AsB, const uint16_t* Wb,
                                              int r, int g, int qt,
                                              uint16_t* Bs) {
#pragma unroll
  for (int lg = 0; lg < 4; ++lg) {
    const uint16_t* Wq = Wb + lg * 16384 + (qt * 16 + r) * 128 + g * 8;
    const short8 w0 = *(const short8a*)(Wq);
    const short8 w1 = *(const short8a*)(Wq + 32);
    const short8 w2 = *(const short8a*)(Wq + 64);
    const short8 w3 = *(const short8a*)(Wq + 96);
#pragma unroll
    for (int u = 0; u <= lg; ++u) {
      const int t = lg * (lg + 1) / 2 + u;
      bool dum;
      const int arow = trow(t, r, dum);
      f32x4 c = {0.f, 0.f, 0.f, 0.f};
      c = mfma_bf16(*(const short8a*)(AsB + aswz(arow, g * 16)), w0, c);
      c = mfma_bf16(*(const short8a*)(AsB + aswz(arow, 64 + g * 16)), w1, c);
      c = mfma_bf16(*(const short8a*)(AsB + aswz(arow, 128 + g * 16)), w2, c);
      c = mfma_bf16(*(const short8a*)(AsB + aswz(arow, 192 + g * 16)), w3, c);
#pragma unroll
      for (int j = 0; j < 4; ++j) {
        bool cr;
        const int row = trow(t, g * 4 + j, cr);
        if (cr) {
          const int cn = row >> 4, cm = row & 15;
          Bs[cn * 2048 + (qt * 16 + r) * 16 + cm] = f2b(c[j]);
        }
      }
    }
  }
}

// GEMM, fresh accumulate, pack to bf16 pairs mp[t*2+{0,1}].
__device__ __forceinline__ void gemm_pack(const char* AsB, const uint16_t* Wb,
                                          int r, int g, int qt, uint32_t* mp) {
#pragma unroll
  for (int lg = 0; lg < 4; ++lg) {
    const uint16_t* Wq = Wb + lg * 16384 + (qt * 16 + r) * 128 + g * 8;
    const short8 w0 = *(const short8a*)(Wq);
    const short8 w1 = *(const short8a*)(Wq + 32);
    const short8 w2 = *(const short8a*)(Wq + 64);
    const short8 w3 = *(const short8a*)(Wq + 96);
#pragma unroll
    for (int u = 0; u <= lg; ++u) {
      const int t = lg * (lg + 1) / 2 + u;
      bool dum;
      const int arow = trow(t, r, dum);
      f32x4 c = {0.f, 0.f, 0.f, 0.f};
      c = mfma_bf16(*(const short8a*)(AsB + aswz(arow, g * 16)), w0, c);
      c = mfma_bf16(*(const short8a*)(AsB + aswz(arow, 64 + g * 16)), w1, c);
      c = mfma_bf16(*(const short8a*)(AsB + aswz(arow, 128 + g * 16)), w2, c);
      c = mfma_bf16(*(const short8a*)(AsB + aswz(arow, 192 + g * 16)), w3, c);
      mp[t * 2] = (uint32_t)f2b(c[0]) | ((uint32_t)f2b(c[1]) << 16);
      mp[t * 2 + 1] = (uint32_t)f2b(c[2]) | ((uint32_t)f2b(c[3]) << 16);
    }
  }
}

// ---------------------------------------------------------------------------
// K0: prep — bf16-transpose weights ([k][q] -> [q][k]) and build Ccat[16][256].
// ---------------------------------------------------------------------------
__global__ __launch_bounds__(256) void k0_prep(
    const float* __restrict__ mixw, const float* __restrict__ iterw,
    const float* __restrict__ cg,
    uint16_t* __restrict__ wtmix, uint16_t* __restrict__ wtiter,
    uint16_t* __restrict__ ccat) {
  int idx = blockIdx.x * 256 + threadIdx.x;
  const int NMIX = 3 * 4 * 16384, NITR = 2 * 4 * 16384;
  if (idx < NMIX) {
    int il = idx >> 14, rem = idx & 16383, q = rem >> 7, k = rem & 127;
    wtmix[idx] = f2b(mixw[il * 16384 + k * 128 + q]);
  } else if (idx < NMIX + NITR) {
    int o = idx - NMIX;
    int tl = o >> 14, rem = o & 16383, q = rem >> 7, k = rem & 127;
    wtiter[o] = f2b(iterw[tl * 16384 + k * 128 + q]);
  } else if (idx < NMIX + NITR + 4096) {
    int o = idx - NMIX - NITR;
    int mg = o >> 8, ij = o & 255, ig = ij >> 4, jg = ij & 15;
    int l = l_of_m(mg), m = mg - l * l;
    int l1 = l_of_m(ig), i = ig - l1 * l1;
    int l2 = l_of_m(jg), j = jg - l2 * l2;
    ccat[o] = f2b(cg[(l1 * 16 + l2 * 4 + l) * 343 + i * 49 + j * 7 + m]);
  }
}

// ---------------------------------------------------------------------------
// Fused block kernel: 512 threads = 8 waves; wave w owns channel tile qt=w
// for GEMMs and row n=w for the TP.
// LDS 64KB: As = [128 row][128 k] bf16 XOR-swizzled; Bs = [8 n][128 k][16 m]
// bf16 linear; final f32 [128][128] staging overlays both.
// __launch_bounds__(512, 2): 2 waves/EU floor -> 256-VGPR cap, no spills.
// ---------------------------------------------------------------------------
__global__ __launch_bounds__(512, 2) void k_fused(
    const float* __restrict__ f0, const float* __restrict__ f1,
    const float* __restrict__ f2, const float* __restrict__ f3,
    const uint16_t* __restrict__ wtmix, const uint16_t* __restrict__ wtiter,
    const uint16_t* __restrict__ ccat, float* __restrict__ out) {
  __shared__ __align__(16) uint16_t smem[32768];   // 64KB
  char* const AsB = (char*)smem;        // swizzled [128 row][128 k] bf16
  uint16_t* const Bs = smem + 16384;    // Bs[n*2048 + k*16 + m]

  const int tid = threadIdx.x;
  const int lane = tid & 63, wid = tid >> 6;
  const int g = lane >> 4, r = lane & 15;
  const int qt = wid;
  const int nblk = blockIdx.x * 8;

  // zero all LDS (coverage insurance)
  {
    u32a* z = (u32a*)smem;
    for (int i = 0; i < 32; ++i) z[tid + i * 512] = 0;
  }
  __syncthreads();

  // ---- phase 0: stage feats (bf16) into As ----
  for (int i = 0; i < 32; ++i) {
    const int elem = tid + i * 512;
    const int row = elem >> 7, k = elem & 127;
    const int nn = row >> 4, mf = row & 15;
    const int l = l_of_m(mf), loc = mf - l * l;
    const float* F = (l == 0) ? f0 : (l == 1) ? f1 : (l == 2) ? f2 : f3;
    *(u16a*)(AsB + aswz(row, k * 2)) =
        f2b(F[((size_t)(nblk + nn) * (2 * l + 1) + loc) * 128 + k]);
  }
  __syncthreads();

  // ---- mixing: cur = feats@W0 (f32 regs), mixed1 -> Bs, mixed2 -> m2p regs --
  f32x4 cur[10];
#pragma unroll
  for (int t = 0; t < 10; ++t) cur[t] = f32x4{0.f, 0.f, 0.f, 0.f};
  uint32_t m2p[20];
  gemm_app(AsB, wtmix, r, g, qt, cur);
  gemm_stage_bs(AsB, wtmix + 4 * 16384, r, g, qt, Bs);
  gemm_pack(AsB, wtmix + 8 * 16384, r, g, qt, m2p);
  __syncthreads();   // feats reads done; As may be overwritten

  const int ih = g >> 1, jb = (g & 1) * 8;

  // ================= iteration 0 =================
  // stage cur -> As (bf16); Bs already holds mixed1
#pragma unroll
  for (int t = 0; t < 10; ++t)
#pragma unroll
    for (int j = 0; j < 4; ++j) {
      bool cr;
      const int row = trow(t, g * 4 + j, cr);
      if (cr) *(u16a*)(AsB + aswz(row, (qt * 16 + r) * 2)) = f2b(cur[t][j]);
    }
  __syncthreads();

  f32x4 tacc[8];
#pragma unroll
  for (int ki = 0; ki < 8; ++ki) tacc[ki] = f32x4{0.f, 0.f, 0.f, 0.f};
#pragma unroll
  for (int cc = 0; cc < 8; ++cc) {
    const short8 cfr = *(const short8a*)(ccat + r * 256 + cc * 32 + g * 8);
    const int arow = wid * 16 + cc * 2 + ih;
#pragma unroll
    for (int ki = 0; ki < 8; ++ki) {
      const int k = ki * 16 + r;
      const float av = b2f(*(const u16a*)(AsB + aswz(arow, k * 2)));
      const short8 bv = *(const short8a*)&Bs[wid * 2048 + k * 16 + jb];
      short8 pv;
#pragma unroll
      for (int e = 0; e < 8; ++e)
        pv[e] = (short)f2b(av * b2f((uint16_t)bv[e]));
      tacc[ki] = mfma_bf16(cfr, pv, tacc[ki]);
    }
  }
  __syncthreads();   // all As/Bs reads complete before overwrite

  // tp -> As rows of n = wid
#pragma unroll
  for (int ki = 0; ki < 8; ++ki)
#pragma unroll
    for (int j = 0; j < 4; ++j)
      *(u16a*)(AsB + aswz(wid * 16 + g * 4 + j, (ki * 16 + r) * 2)) =
          f2b(tacc[ki][j]);
  __syncthreads();

  // cur += tp @ iter_w[0]; also stage mixed2 -> Bs (TP done reading Bs)
  gemm_app(AsB, wtiter, r, g, qt, cur);
#pragma unroll
  for (int t = 0; t < 10; ++t)
#pragma unroll
    for (int j = 0; j < 4; ++j) {
      bool cr;
      const int row = trow(t, g * 4 + j, cr);
      if (cr) {
        const int cn = row >> 4, cm = row & 15;
        Bs[cn * 2048 + (qt * 16 + r) * 16 + cm] =
            (uint16_t)(m2p[t * 2 + (j >> 1)] >> ((j & 1) * 16));
      }
    }
  __syncthreads();

  // ================= iteration 1 =================
#pragma unroll
  for (int t = 0; t < 10; ++t)
#pragma unroll
    for (int j = 0; j < 4; ++j) {
      bool cr;
      const int row = trow(t, g * 4 + j, cr);
      if (cr) *(u16a*)(AsB + aswz(row, (qt * 16 + r) * 2)) = f2b(cur[t][j]);
    }
  __syncthreads();

#pragma unroll
  for (int ki = 0; ki < 8; ++ki) tacc[ki] = f32x4{0.f, 0.f, 0.f, 0.f};
#pragma unroll
  for (int cc = 0; cc < 8; ++cc) {
    const short8 cfr = *(const short8a*)(ccat + r * 256 + cc * 32 + g * 8);
    const int arow = wid * 16 + cc * 2 + ih;
#pragma unroll
    for (int ki = 0; ki < 8; ++ki) {
      const int k = ki * 16 + r;
      const float av = b2f(*(const u16a*)(AsB + aswz(arow, k * 2)));
      const short8 bv = *(const short8a*)&Bs[wid * 2048 + k * 16 + jb];
      short8 pv;
#pragma unroll
      for (int e = 0; e < 8; ++e)
        pv[e] = (short)f2b(av * b2f((uint16_t)bv[e]));
      tacc[ki] = mfma_bf16(cfr, pv, tacc[ki]);
    }
  }
  __syncthreads();

#pragma unroll
  for (int ki = 0; ki < 8; ++ki)
#pragma unroll
    for (int j = 0; j < 4; ++j)
      *(u16a*)(AsB + aswz(wid * 16 + g * 4 + j, (ki * 16 + r) * 2)) =
          f2b(tacc[ki][j]);
  __syncthreads();

  gemm_app(AsB, wtiter + 4 * 16384, r, g, qt, cur);
  __syncthreads();

  // ---- final: stage f32 in LDS (overlay), coalesced store ----
  floata* fs = (floata*)smem;   // [128 row][128 k] f32 = 64KB
#pragma unroll
  for (int t = 0; t < 10; ++t)
#pragma unroll
    for (int j = 0; j < 4; ++j) {
      bool cr;
      const int row = trow(t, g * 4 + j, cr);
      if (cr) fs[row * 128 + qt * 16 + r] = cur[t][j];
    }
  __syncthreads();
  {
    const int grp = tid >> 5, t32 = tid & 31;
    const int ns = grp >> 1, mh = (grp & 1) * 8;
    for (int m8 = 0; m8 < 8; ++m8) {
      const int m = mh + m8;
      const int l = l_of_m(m), loc = m - l * l;
      float* op = out + (size_t)l * l * NK +
                  ((size_t)(nblk + ns) * (2 * l + 1) + loc) * 128 + t32 * 4;
      *(f32x4a*)op = *(const f32x4a*)(fs + (ns * 16 + m) * 128 + t32 * 4);
    }
  }
}

// ---------------------------------------------------------------------------
extern "C" void kernel_launch(void* const* d_in, const int* in_sizes, int n_in,
                              void* d_out, int out_size, void* d_ws, size_t ws_size,
                              hipStream_t stream) {
  const float* f0    = (const float*)d_in[0];
  const float* f1    = (const float*)d_in[1];
  const float* f2    = (const float*)d_in[2];
  const float* f3    = (const float*)d_in[3];
  const float* mixw  = (const float*)d_in[4];
  const float* iterw = (const float*)d_in[5];
  const float* cg    = (const float*)d_in[6];
  float* out = (float*)d_out;

  // ws (uint16): wtmix 196608 | wtiter 131072 | ccat 4096
  uint16_t* wtmix  = (uint16_t*)d_ws;
  uint16_t* wtiter = wtmix + 196608;
  uint16_t* ccat   = wtiter + 131072;

  k0_prep<<<1296, 256, 0, stream>>>(mixw, iterw, cg, wtmix, wtiter, ccat);
  k_fused<<<2048, 512, 0, stream>>>(f0, f1, f2, f3, wtmix, wtiter, ccat, out);
}